// Round 1
// baseline (772.550 us; speedup 1.0000x reference)
//
#include <hip/hip_runtime.h>
#include <stdint.h>

// FP32->FP64 bit-pulse converter.
// Input:  B x 32 floats, each 0.0f or 1.0f, MSB-first FP32 bit pattern
//         [sign, e7..e0, m22..m0].
// Output: B x 64 floats, MSB-first FP64 bit pattern with:
//         E64 = (E==0) ? 0 : E + 896 ; M64 = M << 29
//         NaN (E==255, M!=0): E64=2047, M64=1<<51 (sign kept)
//         Inf (E==255, M==0): E64=2047, M64=0     (sign kept)
//
// One thread per row. uint4 loads (8 x 16B = full 128B row),
// float4 stores (16 x 16B = full 256B row). Memory-bound: 768 MiB total
// traffic -> ~128 us floor at 6.3 TB/s.

__global__ __launch_bounds__(256) void
fp32_to_fp64_pulse_kernel(const uint4* __restrict__ in,
                          float4* __restrict__ out,
                          int nrows) {
    int row = blockIdx.x * blockDim.x + threadIdx.x;
    if (row >= nrows) return;

    const uint4* ip = in + (size_t)row * 8;   // 32 floats = 8 uint4

    // Pack 32 pulse bits into u: bit k = input element k (nonzero float -> 1).
    uint32_t u = 0;
#pragma unroll
    for (int i = 0; i < 8; ++i) {
        uint4 q = ip[i];
        u |= (q.x ? 1u : 0u) << (4 * i + 0);
        u |= (q.y ? 1u : 0u) << (4 * i + 1);
        u |= (q.z ? 1u : 0u) << (4 * i + 2);
        u |= (q.w ? 1u : 0u) << (4 * i + 3);
    }

    // Input is MSB-first, so bit-reverse gives the standard IEEE FP32 word.
    uint32_t v = __brev(u);
    uint32_t E = (v >> 23) & 0xffu;
    uint32_t M = v & 0x7fffffu;
    uint64_t S = (uint64_t)(v >> 31);

    uint64_t E64 = (E == 0u) ? 0ull : (uint64_t)(E + 896u);  // rebias 1023-127
    uint64_t M64 = (uint64_t)M << 29;
    if (E == 255u) {                     // Inf / NaN
        E64 = 2047ull;
        M64 = M ? (1ull << 51) : 0ull;   // quiet NaN: only mantissa MSB set
    }
    uint64_t v64 = (S << 63) | (E64 << 52) | M64;

    // Output element j = bit (63-j) of v64 -> bit-reverse once.
    uint64_t r = __brevll(v64);

    float4* op = out + (size_t)row * 16;  // 64 floats = 16 float4
#pragma unroll
    for (int i = 0; i < 16; ++i) {
        float4 f;
        f.x = ((r >> (4 * i + 0)) & 1ull) ? 1.0f : 0.0f;
        f.y = ((r >> (4 * i + 1)) & 1ull) ? 1.0f : 0.0f;
        f.z = ((r >> (4 * i + 2)) & 1ull) ? 1.0f : 0.0f;
        f.w = ((r >> (4 * i + 3)) & 1ull) ? 1.0f : 0.0f;
        op[i] = f;
    }
}

extern "C" void kernel_launch(void* const* d_in, const int* in_sizes, int n_in,
                              void* d_out, int out_size, void* d_ws, size_t ws_size,
                              hipStream_t stream) {
    (void)n_in; (void)d_ws; (void)ws_size; (void)out_size;
    const uint4* in = (const uint4*)d_in[0];
    float4* out = (float4*)d_out;
    int nrows = in_sizes[0] / 32;          // B = 2097152
    const int block = 256;
    int grid = (nrows + block - 1) / block;
    fp32_to_fp64_pulse_kernel<<<grid, block, 0, stream>>>(in, out, nrows);
}

// Round 2
// 673.936 us; speedup vs baseline: 1.1463x; 1.1463x over previous
//
#include <hip/hip_runtime.h>
#include <stdint.h>

// FP32->FP64 bit-pulse converter, wave-coalesced version.
//
// Input:  B x 32 floats (0.0/1.0), MSB-first FP32 bit pattern per row.
// Output: B x 64 floats, MSB-first FP64 bit pattern:
//   E64 = (E==0) ? 0 : E+896 ; M64 = M<<29
//   NaN (E==255,M!=0): E64=2047, M64=1<<51 ; Inf: E64=2047, M64=0
//
// Layout: one wave (64 lanes) handles 8 rows.
//   Load:  lane k loads float4 #k of the 1024-B tile (perfectly coalesced).
//   Pack:  4 ballots -> 256 bits of the tile in wave-uniform masks.
//   Each lane rebuilds row (lane/8)'s 32-bit word via nibble-spread interleave.
//   Store: lane k writes float4 chunks 2k, 2k+1 of the 2048-B output tile
//          (two stride-2 stores; wave jointly covers contiguous lines).

__device__ __forceinline__ uint32_t spread4(uint32_t x) {
    // spread low 8 bits: bit i -> bit 4*i
    x &= 0xffu;
    x = (x | (x << 12)) & 0x000F000Fu;
    x = (x | (x << 6))  & 0x03030303u;
    x = (x | (x << 3))  & 0x11111111u;
    return x;
}

__global__ __launch_bounds__(256) void
fp32_to_fp64_pulse_kernel(const float4* __restrict__ in,
                          float4* __restrict__ out,
                          int nwaves) {
    int lane = threadIdx.x & 63;
    int w = (int)((blockIdx.x * blockDim.x + threadIdx.x) >> 6);
    if (w >= nwaves) return;  // wave-uniform guard (nwaves*64 == grid threads)

    // ---- coalesced load: 8 rows = 64 float4 ----
    float4 g = in[(size_t)w * 64 + lane];

    // ---- pack all 256 tile bits into 4 wave-uniform 64-bit masks ----
    // bit k of bc == (element 4k+c of tile) != 0
    uint64_t b0 = __ballot(g.x != 0.0f);
    uint64_t b1 = __ballot(g.y != 0.0f);
    uint64_t b2 = __ballot(g.z != 0.0f);
    uint64_t b3 = __ballot(g.w != 0.0f);

    // ---- rebuild this lane's row word (row r = lane/8, MSB-first bits) ----
    int sh = lane & 56;  // 8 * (lane/8)
    uint32_t u = spread4((uint32_t)(b0 >> sh))
               | (spread4((uint32_t)(b1 >> sh)) << 1)
               | (spread4((uint32_t)(b2 >> sh)) << 2)
               | (spread4((uint32_t)(b3 >> sh)) << 3);
    // u bit j == element j of the row (j=0 is sign, MSB-first pulse order)

    // ---- FP32 -> FP64 bit conversion ----
    uint32_t v = __brev(u);              // standard IEEE FP32 word
    uint32_t E = (v >> 23) & 0xffu;
    uint32_t M = v & 0x7fffffu;
    uint64_t S = (uint64_t)(v >> 31);

    uint64_t E64 = E ? (uint64_t)(E + 896u) : 0ull;  // rebias 1023-127
    uint64_t M64 = (uint64_t)M << 29;
    if (E == 255u) {                     // Inf / NaN
        E64 = 2047ull;
        M64 = M ? (1ull << 51) : 0ull;   // quiet NaN: mantissa MSB only
    }
    uint64_t v64 = (S << 63) | (E64 << 52) | M64;
    uint64_t rr  = __brevll(v64);        // rr bit j == output element j of row

    // ---- stores: lane k -> chunks 2k, 2k+1 ----
    // local chunk cc = 2*(lane&7); elements 4cc..4cc+7 == rr bits 8*(lane&7)..+7
    uint32_t ob = (uint32_t)(rr >> ((lane & 7) * 8)) & 0xffu;
    float4 f1, f2;
    f1.x = (ob & 1u)        ? 1.0f : 0.0f;
    f1.y = ((ob >> 1) & 1u) ? 1.0f : 0.0f;
    f1.z = ((ob >> 2) & 1u) ? 1.0f : 0.0f;
    f1.w = ((ob >> 3) & 1u) ? 1.0f : 0.0f;
    f2.x = ((ob >> 4) & 1u) ? 1.0f : 0.0f;
    f2.y = ((ob >> 5) & 1u) ? 1.0f : 0.0f;
    f2.z = ((ob >> 6) & 1u) ? 1.0f : 0.0f;
    f2.w = ((ob >> 7) & 1u) ? 1.0f : 0.0f;

    size_t ob_idx = (size_t)w * 128 + ((size_t)lane << 1);
    out[ob_idx]     = f1;
    out[ob_idx + 1] = f2;
}

extern "C" void kernel_launch(void* const* d_in, const int* in_sizes, int n_in,
                              void* d_out, int out_size, void* d_ws, size_t ws_size,
                              hipStream_t stream) {
    (void)n_in; (void)d_ws; (void)ws_size; (void)out_size;
    const float4* in = (const float4*)d_in[0];
    float4* out = (float4*)d_out;
    int nrows  = in_sizes[0] / 32;       // B = 2097152
    int nwaves = nrows / 8;              // 8 rows per wave (B divisible by 8)
    int threads = nwaves * 64;
    const int block = 256;
    int grid = (threads + block - 1) / block;
    fp32_to_fp64_pulse_kernel<<<grid, block, 0, stream>>>(in, out, nwaves);
}